// Round 18
// baseline (99.132 us; speedup 1.0000x reference)
//
#include <hip/hip_runtime.h>
#include <hip/hip_fp16.h>

typedef _Float16 half8 __attribute__((ext_vector_type(8)));
typedef _Float16 half2v __attribute__((ext_vector_type(2)));
typedef float f32x16 __attribute__((ext_vector_type(16)));
typedef float f32x4v __attribute__((ext_vector_type(4)));

#define MFMA16(A, B, C) __builtin_amdgcn_mfma_f32_32x32x16_f16((A), (B), (C), 0, 0, 0)

__device__ __forceinline__ f32x16 fzero16() {
  f32x16 z;
#pragma unroll
  for (int i = 0; i < 16; ++i) z[i] = 0.0f;
  return z;
}

__device__ __forceinline__ float max16(float vm, const f32x16& s) {
  const float g1 = fmaxf(fmaxf(s[0], s[1]), s[2]);
  const float g2 = fmaxf(fmaxf(s[3], s[4]), s[5]);
  const float g3 = fmaxf(fmaxf(s[6], s[7]), s[8]);
  const float g4 = fmaxf(fmaxf(s[9], s[10]), s[11]);
  const float g5 = fmaxf(fmaxf(s[12], s[13]), s[14]);
  const float h1 = fmaxf(fmaxf(g1, g2), g3);
  const float h2 = fmaxf(fmaxf(g4, g5), s[15]);
  return fmaxf(fmaxf(vm, h1), h2);
}

// ---------------------------------------------------------------------------
// wprep v3: plain-fp16 weights in MFMA-fragment layout; 40 blocks. (kept)
// ---------------------------------------------------------------------------
__global__ __launch_bounds__(256) void wprep_kernel(
    const float* __restrict__ w1, const float* __restrict__ w2,
    const float* __restrict__ w3,
    _Float16* __restrict__ w1p, _Float16* __restrict__ w2p,
    _Float16* __restrict__ w3p)
{
  const int t = threadIdx.x;
  const int blk = blockIdx.x;
  if (blk < 32) {
    const int cot = blk >> 2, sub = blk & 3;
    for (int e = sub * 2048 + t; e < sub * 2048 + 2048; e += 256) {
      const int j = e & 7, l = (e >> 3) & 63, cs = e >> 9;
      const int lr = l & 31, h = l >> 5;
      const int row = cot * 32 + lr;
      const int col = cs * 16 + 4 * h + (j & 3) + 8 * (j >> 2);
      w3p[((cot * 16 + cs) * 64 + l) * 8 + j] = (_Float16)w3[row * 256 + col];
    }
  } else {
    const int sub = blk - 32;   // 0..7
    for (int e = sub * 1024 + t; e < sub * 1024 + 1024; e += 256) {
      const int j = e & 7, l = (e >> 3) & 63, cs = e >> 9;
      const int lr = l & 31, h = l >> 5;
      const int col = cs * 16 + 4 * h + (j & 3) + 8 * (j >> 2);
      const int idx = (cs * 64 + l) * 8 + j;
      w1p[idx] = (_Float16)w1[lr * 256 + col];
      w2p[idx] = (_Float16)w2[lr * 256 + col];
    }
  }
}

// ---------------------------------------------------------------------------
// FUSED qkv projection v3 — plain fp16. (kept)
// ---------------------------------------------------------------------------
__global__ __launch_bounds__(256) void qkv_proj_kernel(
    const float* __restrict__ x,
    const _Float16* __restrict__ w1p, const float* __restrict__ b1,
    const _Float16* __restrict__ w2p, const float* __restrict__ b2,
    const _Float16* __restrict__ w3p, const float* __restrict__ b3,
    _Float16* __restrict__ qb, _Float16* __restrict__ kb,
    _Float16* __restrict__ vb)
{
  __shared__ f32x4v red[4][2][4][64];   // [wave][q/k][i4][lane], 32 KB
  const int t = threadIdx.x, w = t >> 6, l = t & 63;
  const int lr = l & 31, h = l >> 5;
  const int b = blockIdx.x >> 7;
  const int nt = blockIdx.x & 127;
  const float* xb = x + (size_t)b * 256 * 4096 + nt * 32 + lr;
  const int cot0 = w * 2, cot1 = w * 2 + 1;

  f32x16 accq = fzero16(), acck = fzero16();
  f32x16 accv0 = fzero16(), accv1 = fzero16();

  for (int cs = 0; cs < 16; ++cs) {
    const int c0 = cs * 16 + 4 * h;
    half8 xh;
#pragma unroll
    for (int j = 0; j < 8; ++j) {
      const int c = c0 + (j & 3) + 8 * (j >> 2);
      xh[j] = (_Float16)xb[(size_t)c * 4096];
    }
    const half8 wh0 = *(const half8*)&w3p[((cot0 * 16 + cs) * 64 + l) * 8];
    const half8 wh1 = *(const half8*)&w3p[((cot1 * 16 + cs) * 64 + l) * 8];
    accv0 = MFMA16(xh, wh0, accv0);
    accv1 = MFMA16(xh, wh1, accv1);
    if ((cs >> 2) == w) {
      const half8 w1h = *(const half8*)&w1p[(cs * 64 + l) * 8];
      const half8 w2h = *(const half8*)&w2p[(cs * 64 + l) * 8];
      accq = MFMA16(w1h, xh, accq);
      acck = MFMA16(w2h, xh, acck);
    }
  }

  const float bv0 = b3[cot0 * 32 + lr];
  const float bv1 = b3[cot1 * 32 + lr];
#pragma unroll
  for (int hfq = 0; hfq < 2; ++hfq) {
    half8 p0, p1;
#pragma unroll
    for (int j = 0; j < 8; ++j) {
      p0[j] = (_Float16)(accv0[8 * hfq + j] + bv0);
      p1[j] = (_Float16)(accv1[8 * hfq + j] + bv1);
    }
    const int ms = nt * 2 + hfq;
    *(half8*)&vb[((((size_t)b * 256 + ms) * 8 + cot0) * 64 + l) * 8] = p0;
    *(half8*)&vb[((((size_t)b * 256 + ms) * 8 + cot1) * 64 + l) * 8] = p1;
  }

#pragma unroll
  for (int i4 = 0; i4 < 4; ++i4) {
    f32x4v q4, k4;
#pragma unroll
    for (int c = 0; c < 4; ++c) { q4[c] = accq[4 * i4 + c]; k4[c] = acck[4 * i4 + c]; }
    red[w][0][i4][l] = q4;
    red[w][1][i4][l] = k4;
  }
  __syncthreads();
  if (w < 2) {
    _Float16* dst = (w == 0) ? qb : kb;
    const float* bias = (w == 0) ? b1 : b2;
    f32x16 tot;
#pragma unroll
    for (int i4 = 0; i4 < 4; ++i4) {
      f32x4v v = red[0][w][i4][l];
      v += red[1][w][i4][l];
      v += red[2][w][i4][l];
      v += red[3][w][i4][l];
#pragma unroll
      for (int c = 0; c < 4; ++c) tot[4 * i4 + c] = v[c];
    }
#pragma unroll
    for (int ds = 0; ds < 2; ++ds) {
      half8 ph;
#pragma unroll
      for (int j = 0; j < 8; ++j) {
        const int d = 16 * ds + 4 * h + (j & 3) + 8 * (j >> 2);
        ph[j] = (_Float16)(tot[8 * ds + j] + bias[d]);
      }
      *(half8*)&dst[((((size_t)b * 128 + nt) * 2 + ds) * 64 + l) * 8] = ph;
    }
  }
}

// ---------------------------------------------------------------------------
// attn v16: BARRIER-FREE self-consumption. 8 waves/block, 64 rows (2 slabs),
// grid 256. Wave (sw=w>>2, kq=w&3): slab sw, keys [kq*1024,(kq+1)*1024),
// ALL 256 couts in 2 passes of 128 (acc = 4 f32x16). Per 32-key tile:
// QK -> exp -> pack; the packed u0/u1 regs ARE the PV B-operand (same lane,
// v5-proven) -> PV vs 4 cout-tiles from register V (depth-1 double buffer).
// NO barriers, NO LDS in the main loop. Fused prefetched rowmax scan.
// Epilogue: 4-way key-partial combine via 64KB LDS (2 chunks/pass).
// XCD swizzle: batch b -> XCDs {2b,2b+1}. launch_bounds(512,2).
// ---------------------------------------------------------------------------
__global__ __launch_bounds__(512, 2) void attn_kernel(
    const _Float16* __restrict__ qb, const _Float16* __restrict__ kb,
    const _Float16* __restrict__ vb,
    const float* __restrict__ x, float* __restrict__ out)
{
  __shared__ float comb[8 * 2 * 16 * 64];   // 64 KB combine buffer
  __shared__ float Mred[2][4][32];
  __shared__ float Lred[2][4][32];
  const int t = threadIdx.x, w = t >> 6, l = t & 63;
  const int lr = l & 31, h = l >> 5;
  const int bid = blockIdx.x;
  const int xcd = bid & 7;
  const int b = xcd >> 1;
  const int rg = ((bid >> 3) << 1) | (xcd & 1);   // 64-row group [0,64)
  const int sw = w >> 2;                           // slab
  const int kq = w & 3;                            // key quarter
  const int m0 = kq * 32;                          // first 32-key tile

  const _Float16* kbase = kb + (size_t)b * 131072 + (size_t)l * 8;
  const _Float16* vbase = vb + (size_t)b * 1048576 + (size_t)l * 8;

#define KFM(m, ds) (*(const half8*)(kbase + ((size_t)((m) * 2 + (ds))) * 512))
#define VFm(m, ks, ct, PS) (*(const half8*)(vbase + ((size_t)((((m) * 2 + (ks)) * 8) + ((PS) * 4 + (ct)))) * 512))

  const int rt32q = rg * 2 + sw;
  const _Float16* qp = qb + (((size_t)b * 128 + rt32q) * 2 * 64 + l) * 8;
  const half8 qf0 = *(const half8*)qp;
  const half8 qf1 = *(const half8*)(qp + 512);
  const float LOG2E = 1.44269504088896340736f;

  // ---- fused rowmax scan: own 32 tiles, depth-1 K prefetch ----
  {
    float vm = -3.0e38f;
    half8 sk0 = KFM(m0, 0), sk1 = KFM(m0, 1);
    for (int m = m0; m < m0 + 32; ++m) {
      half8 nk0, nk1;
      if (m + 1 < m0 + 32) { nk0 = KFM(m + 1, 0); nk1 = KFM(m + 1, 1); }
      f32x16 s = fzero16();
      s = MFMA16(sk0, qf0, s);
      s = MFMA16(sk1, qf1, s);
      vm = max16(vm, s);
      sk0 = nk0; sk1 = nk1;
    }
    vm = fmaxf(vm, __shfl_xor(vm, 32));
    if (l < 32) Mred[sw][kq][lr] = vm;
  }
  __syncthreads();
  const float Mr = fmaxf(fmaxf(Mred[sw][0][lr], Mred[sw][1][lr]),
                         fmaxf(Mred[sw][2][lr], Mred[sw][3][lr]));
  const float nM2 = -Mr * LOG2E;

  float Lacc = 0.f;
  const float* xb = x + (size_t)b * 1048576;
  float* ob = out + (size_t)b * 1048576;

#define EXPP(S, PS)                                                            \
  {                                                                            \
    float pvv[16];                                                             \
    float ls = 0.f;                                                            \
    _Pragma("unroll") for (int i = 0; i < 16; ++i) {                           \
      pvv[i] = exp2f(fmaf((S)[i], LOG2E, nM2)); ls += pvv[i];                  \
    }                                                                          \
    if ((PS) == 0) Lacc += ls;                                                 \
    union { half8 v; half2v h2[4]; } uu0, uu1;                                 \
    _Pragma("unroll") for (int jj = 0; jj < 4; ++jj) {                         \
      auto a0 = __builtin_amdgcn_cvt_pkrtz(pvv[2 * jj], pvv[2 * jj + 1]);      \
      auto a1 = __builtin_amdgcn_cvt_pkrtz(pvv[8 + 2 * jj], pvv[8 + 2 * jj + 1]); \
      uu0.h2[jj] = *(half2v*)&a0;                                              \
      uu1.h2[jj] = *(half2v*)&a1;                                              \
    }                                                                          \
    u0c = uu0.v; u1c = uu1.v;                                                  \
  }

#define PVCONS(VC)                                                             \
  {                                                                            \
    __builtin_amdgcn_s_setprio(1);                                             \
    _Pragma("unroll") for (int ct = 0; ct < 4; ++ct) {                         \
      acc[ct] = MFMA16(VC[ct * 2 + 0], u0c, acc[ct]);                          \
      acc[ct] = MFMA16(VC[ct * 2 + 1], u1c, acc[ct]);                          \
    }                                                                          \
    __builtin_amdgcn_s_setprio(0);                                             \
  }

#define PBODY(I, VC, VN, PS)                                                   \
  {                                                                            \
    _Pragma("unroll") for (int e = 0; e < 8; ++e)                              \
      VN[e] = VFm(m0 + (I) + 1, (e)&1, (e) >> 1, PS);                          \
    f32x16 s = fzero16();                                                      \
    s = MFMA16(kc0, qf0, s);                                                   \
    s = MFMA16(kc1, qf1, s);                                                   \
    if ((I) + 2 < 32) { kc0 = KFM(m0 + (I) + 2, 0); kc1 = KFM(m0 + (I) + 2, 1); } \
    PVCONS(VC)                                                                 \
    EXPP(s, PS)                                                                \
  }

  for (int ps = 0; ps < 2; ++ps) {
    f32x16 acc[4];
#pragma unroll
    for (int ct = 0; ct < 4; ++ct) acc[ct] = fzero16();
    half8 VA[8], VB[8];
    half8 kc0, kc1, u0c, u1c;

    // pass prologue: V(tile 0), QK(tile 0) -> u
#pragma unroll
    for (int e = 0; e < 8; ++e) VA[e] = VFm(m0, e & 1, e >> 1, ps);
    kc0 = KFM(m0, 0); kc1 = KFM(m0, 1);
    {
      f32x16 s = fzero16();
      s = MFMA16(kc0, qf0, s);
      s = MFMA16(kc1, qf1, s);
      kc0 = KFM(m0 + 1, 0); kc1 = KFM(m0 + 1, 1);
      EXPP(s, ps)
    }

    for (int i = 0; i < 30; i += 2) {
      PBODY(i, VA, VB, ps)
      PBODY(i + 1, VB, VA, ps)
    }
    PBODY(30, VA, VB, ps)
    PVCONS(VB)   // tail: tile 31

    // ---- combine 4 key-partials per slab, 2 chunks of 2 cout-tiles ----
    if (ps == 0) {
      const float l2 = Lacc + __shfl_xor(Lacc, 32);
      if (l < 32) Lred[sw][kq][lr] = l2;
    }
#pragma unroll
    for (int c = 0; c < 2; ++c) {
      __syncthreads();
#pragma unroll
      for (int ctc = 0; ctc < 2; ++ctc)
#pragma unroll
        for (int reg = 0; reg < 16; ++reg)
          comb[((w * 2 + ctc) * 16 + reg) * 64 + l] = acc[c * 2 + ctc][reg];
      __syncthreads();
      const int s2 = w >> 2, ctc2 = (w >> 1) & 1, hf = w & 1;
      const float invL = 1.0f / (Lred[s2][0][lr] + Lred[s2][1][lr] +
                                 Lred[s2][2][lr] + Lred[s2][3][lr]);
      const int nn = rg * 64 + s2 * 32 + lr;
#pragma unroll
      for (int r8 = 0; r8 < 8; ++r8) {
        const int reg = hf * 8 + r8;
        float sum = comb[(((s2 * 4 + 0) * 2 + ctc2) * 16 + reg) * 64 + l];
        sum += comb[(((s2 * 4 + 1) * 2 + ctc2) * 16 + reg) * 64 + l];
        sum += comb[(((s2 * 4 + 2) * 2 + ctc2) * 16 + reg) * 64 + l];
        sum += comb[(((s2 * 4 + 3) * 2 + ctc2) * 16 + reg) * 64 + l];
        const int crel = (reg & 3) + 8 * (reg >> 2) + 4 * h;
        const int cout = (ps * 4 + c * 2 + ctc2) * 32 + crel;
        const size_t o = (size_t)cout * 4096 + nn;
        ob[o] = sum * invL + xb[o];
      }
    }
  }
#undef PBODY
#undef PVCONS
#undef EXPP
#undef KFM
#undef VFm
}

extern "C" void kernel_launch(void* const* d_in, const int* in_sizes, int n_in,
                              void* d_out, int out_size, void* d_ws, size_t ws_size,
                              hipStream_t stream) {
  const float* x  = (const float*)d_in[0];
  const float* w1 = (const float*)d_in[1];
  const float* b1 = (const float*)d_in[2];
  const float* w2 = (const float*)d_in[3];
  const float* b2 = (const float*)d_in[4];
  const float* w3 = (const float*)d_in[5];
  const float* b3 = (const float*)d_in[6];
  float* out = (float*)d_out;

  char* ws = (char*)d_ws;
  _Float16* qb  = (_Float16*)(ws);                               // 1 MB
  _Float16* kb  = (_Float16*)(ws + (1u << 20));                  // 1 MB
  _Float16* vb  = (_Float16*)(ws + (2u << 20));                  // 8 MB
  _Float16* w1p = (_Float16*)(ws + (10u << 20) + (64u << 10));   // 16 KB
  _Float16* w2p = (_Float16*)(ws + (10u << 20) + (96u << 10));   // 16 KB
  _Float16* w3p = (_Float16*)(ws + (10u << 20) + (128u << 10));  // 128 KB

  hipLaunchKernelGGL(wprep_kernel, dim3(40), dim3(256), 0, stream,
                     w1, w2, w3, w1p, w2p, w3p);
  hipLaunchKernelGGL(qkv_proj_kernel, dim3(512), dim3(256), 0, stream,
                     x, w1p, b1, w2p, b2, w3p, b3, qb, kb, vb);
  hipLaunchKernelGGL(attn_kernel, dim3(256), dim3(512), 0, stream,
                     qb, kb, vb, x, out);
}

// Round 19
// 73.153 us; speedup vs baseline: 1.3551x; 1.3551x over previous
//
#include <hip/hip_runtime.h>
#include <hip/hip_fp16.h>

typedef _Float16 half8 __attribute__((ext_vector_type(8)));
typedef _Float16 half2v __attribute__((ext_vector_type(2)));
typedef float f32x16 __attribute__((ext_vector_type(16)));
typedef float f32x4v __attribute__((ext_vector_type(4)));

#define MFMA16(A, B, C) __builtin_amdgcn_mfma_f32_32x32x16_f16((A), (B), (C), 0, 0, 0)

__device__ __forceinline__ f32x16 fzero16() {
  f32x16 z;
#pragma unroll
  for (int i = 0; i < 16; ++i) z[i] = 0.0f;
  return z;
}

__device__ __forceinline__ float max16(float vm, const f32x16& s) {
  const float g1 = fmaxf(fmaxf(s[0], s[1]), s[2]);
  const float g2 = fmaxf(fmaxf(s[3], s[4]), s[5]);
  const float g3 = fmaxf(fmaxf(s[6], s[7]), s[8]);
  const float g4 = fmaxf(fmaxf(s[9], s[10]), s[11]);
  const float g5 = fmaxf(fmaxf(s[12], s[13]), s[14]);
  const float h1 = fmaxf(fmaxf(g1, g2), g3);
  const float h2 = fmaxf(fmaxf(g4, g5), s[15]);
  return fmaxf(fmaxf(vm, h1), h2);
}

// ---------------------------------------------------------------------------
// wprep v3: plain-fp16 weights in MFMA-fragment layout; 40 blocks.
// ---------------------------------------------------------------------------
__global__ __launch_bounds__(256) void wprep_kernel(
    const float* __restrict__ w1, const float* __restrict__ w2,
    const float* __restrict__ w3,
    _Float16* __restrict__ w1p, _Float16* __restrict__ w2p,
    _Float16* __restrict__ w3p)
{
  const int t = threadIdx.x;
  const int blk = blockIdx.x;
  if (blk < 32) {
    const int cot = blk >> 2, sub = blk & 3;
    for (int e = sub * 2048 + t; e < sub * 2048 + 2048; e += 256) {
      const int j = e & 7, l = (e >> 3) & 63, cs = e >> 9;
      const int lr = l & 31, h = l >> 5;
      const int row = cot * 32 + lr;
      const int col = cs * 16 + 4 * h + (j & 3) + 8 * (j >> 2);
      w3p[((cot * 16 + cs) * 64 + l) * 8 + j] = (_Float16)w3[row * 256 + col];
    }
  } else {
    const int sub = blk - 32;   // 0..7
    for (int e = sub * 1024 + t; e < sub * 1024 + 1024; e += 256) {
      const int j = e & 7, l = (e >> 3) & 63, cs = e >> 9;
      const int lr = l & 31, h = l >> 5;
      const int col = cs * 16 + 4 * h + (j & 3) + 8 * (j >> 2);
      const int idx = (cs * 64 + l) * 8 + j;
      w1p[idx] = (_Float16)w1[lr * 256 + col];
      w2p[idx] = (_Float16)w2[lr * 256 + col];
    }
  }
}

// ---------------------------------------------------------------------------
// FUSED qkv projection v3 — plain fp16 (r14, measured best).
// ---------------------------------------------------------------------------
__global__ __launch_bounds__(256) void qkv_proj_kernel(
    const float* __restrict__ x,
    const _Float16* __restrict__ w1p, const float* __restrict__ b1,
    const _Float16* __restrict__ w2p, const float* __restrict__ b2,
    const _Float16* __restrict__ w3p, const float* __restrict__ b3,
    _Float16* __restrict__ qb, _Float16* __restrict__ kb,
    _Float16* __restrict__ vb)
{
  __shared__ f32x4v red[4][2][4][64];   // [wave][q/k][i4][lane], 32 KB
  const int t = threadIdx.x, w = t >> 6, l = t & 63;
  const int lr = l & 31, h = l >> 5;
  const int b = blockIdx.x >> 7;
  const int nt = blockIdx.x & 127;
  const float* xb = x + (size_t)b * 256 * 4096 + nt * 32 + lr;
  const int cot0 = w * 2, cot1 = w * 2 + 1;

  f32x16 accq = fzero16(), acck = fzero16();
  f32x16 accv0 = fzero16(), accv1 = fzero16();

  for (int cs = 0; cs < 16; ++cs) {
    const int c0 = cs * 16 + 4 * h;
    half8 xh;
#pragma unroll
    for (int j = 0; j < 8; ++j) {
      const int c = c0 + (j & 3) + 8 * (j >> 2);
      xh[j] = (_Float16)xb[(size_t)c * 4096];
    }
    const half8 wh0 = *(const half8*)&w3p[((cot0 * 16 + cs) * 64 + l) * 8];
    const half8 wh1 = *(const half8*)&w3p[((cot1 * 16 + cs) * 64 + l) * 8];
    accv0 = MFMA16(xh, wh0, accv0);
    accv1 = MFMA16(xh, wh1, accv1);
    if ((cs >> 2) == w) {
      const half8 w1h = *(const half8*)&w1p[(cs * 64 + l) * 8];
      const half8 w2h = *(const half8*)&w2p[(cs * 64 + l) * 8];
      accq = MFMA16(w1h, xh, accq);
      acck = MFMA16(w2h, xh, acck);
    }
  }

  const float bv0 = b3[cot0 * 32 + lr];
  const float bv1 = b3[cot1 * 32 + lr];
#pragma unroll
  for (int hfq = 0; hfq < 2; ++hfq) {
    half8 p0, p1;
#pragma unroll
    for (int j = 0; j < 8; ++j) {
      p0[j] = (_Float16)(accv0[8 * hfq + j] + bv0);
      p1[j] = (_Float16)(accv1[8 * hfq + j] + bv1);
    }
    const int ms = nt * 2 + hfq;
    *(half8*)&vb[((((size_t)b * 256 + ms) * 8 + cot0) * 64 + l) * 8] = p0;
    *(half8*)&vb[((((size_t)b * 256 + ms) * 8 + cot1) * 64 + l) * 8] = p1;
  }

#pragma unroll
  for (int i4 = 0; i4 < 4; ++i4) {
    f32x4v q4, k4;
#pragma unroll
    for (int c = 0; c < 4; ++c) { q4[c] = accq[4 * i4 + c]; k4[c] = acck[4 * i4 + c]; }
    red[w][0][i4][l] = q4;
    red[w][1][i4][l] = k4;
  }
  __syncthreads();
  if (w < 2) {
    _Float16* dst = (w == 0) ? qb : kb;
    const float* bias = (w == 0) ? b1 : b2;
    f32x16 tot;
#pragma unroll
    for (int i4 = 0; i4 < 4; ++i4) {
      f32x4v v = red[0][w][i4][l];
      v += red[1][w][i4][l];
      v += red[2][w][i4][l];
      v += red[3][w][i4][l];
#pragma unroll
      for (int c = 0; c < 4; ++c) tot[4 * i4 + c] = v[c];
    }
#pragma unroll
    for (int ds = 0; ds < 2; ++ds) {
      half8 ph;
#pragma unroll
      for (int j = 0; j < 8; ++j) {
        const int d = 16 * ds + 4 * h + (j & 3) + 8 * (j >> 2);
        ph[j] = (_Float16)(tot[8 * ds + j] + bias[d]);
      }
      *(half8*)&dst[((((size_t)b * 128 + nt) * 2 + ds) * 64 + l) * 8] = ph;
    }
  }
}

// ---------------------------------------------------------------------------
// rowmax v4 (r14, measured best). Bitwise-identical MFMA order to attn QK.
// ---------------------------------------------------------------------------
__global__ __launch_bounds__(512) void rowmax_kernel(
    const _Float16* __restrict__ qb, const _Float16* __restrict__ kb,
    float* __restrict__ Mrow)
{
  __shared__ float red[2][8][32];
  const int t = threadIdx.x, w = t >> 6, l = t & 63;
  const int bid = blockIdx.x;
  const int xcd = bid & 7;
  const int b = xcd >> 1;
  const int sp = ((bid >> 3) << 1) | (xcd & 1);   // slab pair [0,64)
  const int sl0 = sp * 2, sl1 = sp * 2 + 1;
  const _Float16* qp0 = qb + ((((size_t)b * 128 + sl0) * 2) * 64 + l) * 8;
  const _Float16* qp1 = qb + ((((size_t)b * 128 + sl1) * 2) * 64 + l) * 8;
  const half8 q00 = *(const half8*)qp0;
  const half8 q01 = *(const half8*)(qp0 + 512);
  const half8 q10 = *(const half8*)qp1;
  const half8 q11 = *(const half8*)(qp1 + 512);
  float vm0 = -3.0e38f, vm1 = -3.0e38f;
  for (int mt = w * 16; mt < w * 16 + 16; ++mt) {
    const _Float16* kp = kb + ((((size_t)b * 128 + mt) * 2) * 64 + l) * 8;
    const half8 k0 = *(const half8*)kp;
    const half8 k1 = *(const half8*)(kp + 512);
    f32x16 s0 = fzero16();
    s0 = MFMA16(k0, q00, s0);
    s0 = MFMA16(k1, q01, s0);
    f32x16 s1 = fzero16();
    s1 = MFMA16(k0, q10, s1);
    s1 = MFMA16(k1, q11, s1);
    vm0 = max16(vm0, s0);
    vm1 = max16(vm1, s1);
  }
  vm0 = fmaxf(vm0, __shfl_xor(vm0, 32));
  vm1 = fmaxf(vm1, __shfl_xor(vm1, 32));
  if (l < 32) { red[0][w][l] = vm0; red[1][w][l] = vm1; }
  __syncthreads();
  if (t < 64) {
    const int slab = t >> 5, r = t & 31;
    float m = red[slab][0][r];
#pragma unroll
    for (int ww = 1; ww < 8; ++ww) m = fmaxf(m, red[slab][ww][r]);
    Mrow[(size_t)b * 4096 + (sp * 2 + slab) * 32 + r] = m;
  }
}

// ---------------------------------------------------------------------------
// attn v8 VERBATIM (measured 51.3us best): balanced producer/consumer waves,
// one barrier per 256 keys, deep reg prefetch, union pack.
// ---------------------------------------------------------------------------
__global__ __launch_bounds__(512, 1) void attn_kernel(
    const _Float16* __restrict__ qb, const _Float16* __restrict__ kb,
    const _Float16* __restrict__ vb, const float* __restrict__ Mrow,
    const float* __restrict__ x, float* __restrict__ out)
{
  __shared__ __align__(16) _Float16 Plds[2][2][2][8][64][8];  // 64 KB
  __shared__ float Lred[2][4][32];
  const int t = threadIdx.x, w = t >> 6, l = t & 63;
  const int lr = l & 31, h = l >> 5;
  const int bid = blockIdx.x;
  const int xcd = bid & 7;
  const int b = xcd >> 1;
  const int rg = ((bid >> 3) << 1) | (xcd & 1);   // row-group of 64 [0,64)
  const int sw = w >> 2;                           // produced slab
  const int kq = w & 3;                            // produced key-quarter

  const _Float16* kbase = kb + (size_t)b * 131072 + (size_t)l * 8;
  const _Float16* vbase = vb + (size_t)b * 1048576 + (size_t)w * 512 + (size_t)l * 8;

#define KF(kt, ds) (*(const half8*)(kbase + ((size_t)(((kt) * 4 + kq) * 2 + (ds))) * 512))
#define VF(kt, ks) (*(const half8*)(vbase + ((size_t)(((kt) * 8 + (ks)) * 8)) * 512))

  const int rt32q = rg * 2 + sw;
  const _Float16* qp = qb + (((size_t)b * 128 + rt32q) * 2 * 64 + l) * 8;
  const half8 qf0 = *(const half8*)qp;
  const half8 qf1 = *(const half8*)(qp + 512);
  const float LOG2E = 1.44269504088896340736f;
  const float Mr = Mrow[(size_t)b * 4096 + rt32q * 32 + lr];
  const float nM2 = -Mr * LOG2E;

  f32x16 acc0 = fzero16(), acc1 = fzero16();
  float Lacc = 0.f;
  half8 va0[8], va1[8];
  half8 ka0, ka1, kb0_, kb1_;

#define EXPPACK(S, BUF, TI)                                                    \
  {                                                                            \
    float pvv[16];                                                             \
    float ls = 0.f;                                                            \
    _Pragma("unroll") for (int i = 0; i < 16; ++i) {                           \
      pvv[i] = exp2f(fmaf((S)[i], LOG2E, nM2)); ls += pvv[i];                  \
    }                                                                          \
    Lacc += ls;                                                                \
    union { half8 v; half2v h2[4]; } u0, u1;                                   \
    _Pragma("unroll") for (int jj = 0; jj < 4; ++jj) {                         \
      auto a0 = __builtin_amdgcn_cvt_pkrtz(pvv[2 * jj], pvv[2 * jj + 1]);      \
      auto a1 = __builtin_amdgcn_cvt_pkrtz(pvv[8 + 2 * jj], pvv[8 + 2 * jj + 1]); \
      u0.h2[jj] = *(half2v*)&a0;                                               \
      u1.h2[jj] = *(half2v*)&a1;                                               \
    }                                                                          \
    *(half8*)&Plds[BUF][TI][sw][kq * 2 + 0][l][0] = u0.v;                      \
    *(half8*)&Plds[BUF][TI][sw][kq * 2 + 1][l][0] = u1.v;                      \
  }

#define PVC(CB, TI, VA)                                                        \
  {                                                                            \
    __builtin_amdgcn_s_setprio(1);                                             \
    _Pragma("unroll") for (int ks = 0; ks < 8; ++ks) {                         \
      const half8 pb0 = *(const half8*)&Plds[CB][TI][0][ks][l][0];             \
      const half8 pb1 = *(const half8*)&Plds[CB][TI][1][ks][l][0];             \
      acc0 = MFMA16(VA[ks], pb0, acc0);                                        \
      acc1 = MFMA16(VA[ks], pb1, acc1);                                        \
    }                                                                          \
    __builtin_amdgcn_s_setprio(0);                                             \
  }

  // ---- prologue: V(0),V(1) in regs; produce tiles 0,1 -> buf0; K(2),K(3) ----
#pragma unroll
  for (int ks = 0; ks < 8; ++ks) va0[ks] = VF(0, ks);
#pragma unroll
  for (int ks = 0; ks < 8; ++ks) va1[ks] = VF(1, ks);
  {
    const half8 k00 = KF(0, 0), k01 = KF(0, 1);
    f32x16 s = fzero16();
    s = MFMA16(k00, qf0, s);
    s = MFMA16(k01, qf1, s);
    ka0 = KF(2, 0); ka1 = KF(2, 1);
    EXPPACK(s, 0, 0)
  }
  {
    const half8 k10 = KF(1, 0), k11 = KF(1, 1);
    f32x16 s = fzero16();
    s = MFMA16(k10, qf0, s);
    s = MFMA16(k11, qf1, s);
    kb0_ = KF(3, 0); kb1_ = KF(3, 1);
    EXPPACK(s, 0, 1)
  }
  asm volatile("s_waitcnt lgkmcnt(0)" ::: "memory");
  __builtin_amdgcn_s_barrier();
  asm volatile("" ::: "memory");

  // ---- 16 periods of 256 keys, ONE barrier each ----
  for (int P = 0; P < 16; ++P) {
    const int CB = P & 1, PB = CB ^ 1;
    const int p0 = 2 * P + 2, p1 = 2 * P + 3;

    if (p0 < 32) {
      f32x16 s = fzero16();
      s = MFMA16(ka0, qf0, s);
      s = MFMA16(ka1, qf1, s);
      if (p0 + 2 < 32) { ka0 = KF(p0 + 2, 0); ka1 = KF(p0 + 2, 1); }
      EXPPACK(s, PB, 0)
    }
    PVC(CB, 0, va0)
    if (p0 < 32) {
#pragma unroll
      for (int ks = 0; ks < 8; ++ks) va0[ks] = VF(p0, ks);
    }

    if (p1 < 32) {
      f32x16 s = fzero16();
      s = MFMA16(kb0_, qf0, s);
      s = MFMA16(kb1_, qf1, s);
      if (p1 + 2 < 32) { kb0_ = KF(p1 + 2, 0); kb1_ = KF(p1 + 2, 1); }
      EXPPACK(s, PB, 1)
    }
    PVC(CB, 1, va1)
    if (p1 < 32) {
#pragma unroll
      for (int ks = 0; ks < 8; ++ks) va1[ks] = VF(p1, ks);
    }

    asm volatile("s_waitcnt lgkmcnt(0)" ::: "memory");
    __builtin_amdgcn_s_barrier();
    asm volatile("" ::: "memory");
  }
#undef PVC
#undef EXPPACK
#undef KF
#undef VF

  // ---- L reduce: L[slab][row] = sum over 4 quarters ----
  {
    const float l2 = Lacc + __shfl_xor(Lacc, 32);
    if (l < 32) Lred[sw][kq][lr] = l2;
  }
  __syncthreads();
  const float invL0 = 1.0f / (Lred[0][0][lr] + Lred[0][1][lr] + Lred[0][2][lr] + Lred[0][3][lr]);
  const float invL1 = 1.0f / (Lred[1][0][lr] + Lred[1][1][lr] + Lred[1][2][lr] + Lred[1][3][lr]);

  // ---- epilogue: normalize + residual ----
  const float* xb = x + (size_t)b * 1048576;
  float* ob = out + (size_t)b * 1048576;
  const int nn0 = rg * 64 + lr;
  const int nn1 = rg * 64 + 32 + lr;
#pragma unroll
  for (int reg = 0; reg < 16; ++reg) {
    const int crel = (reg & 3) + 8 * (reg >> 2) + 4 * h;
    const int cout = w * 32 + crel;
    const size_t o0 = (size_t)cout * 4096 + nn0;
    ob[o0] = acc0[reg] * invL0 + xb[o0];
    const size_t o1 = (size_t)cout * 4096 + nn1;
    ob[o1] = acc1[reg] * invL1 + xb[o1];
  }
}

extern "C" void kernel_launch(void* const* d_in, const int* in_sizes, int n_in,
                              void* d_out, int out_size, void* d_ws, size_t ws_size,
                              hipStream_t stream) {
  const float* x  = (const float*)d_in[0];
  const float* w1 = (const float*)d_in[1];
  const float* b1 = (const float*)d_in[2];
  const float* w2 = (const float*)d_in[3];
  const float* b2 = (const float*)d_in[4];
  const float* w3 = (const float*)d_in[5];
  const float* b3 = (const float*)d_in[6];
  float* out = (float*)d_out;

  char* ws = (char*)d_ws;
  _Float16* qb  = (_Float16*)(ws);                               // 1 MB
  _Float16* kb  = (_Float16*)(ws + (1u << 20));                  // 1 MB
  _Float16* vb  = (_Float16*)(ws + (2u << 20));                  // 8 MB
  float*    Mrow = (float*)(ws + (10u << 20));                   // 64 KB
  _Float16* w1p = (_Float16*)(ws + (10u << 20) + (64u << 10));   // 16 KB
  _Float16* w2p = (_Float16*)(ws + (10u << 20) + (96u << 10));   // 16 KB
  _Float16* w3p = (_Float16*)(ws + (10u << 20) + (128u << 10));  // 128 KB

  hipLaunchKernelGGL(wprep_kernel, dim3(40), dim3(256), 0, stream,
                     w1, w2, w3, w1p, w2p, w3p);
  hipLaunchKernelGGL(qkv_proj_kernel, dim3(512), dim3(256), 0, stream,
                     x, w1p, b1, w2p, b2, w3p, b3, qb, kb, vb);
  hipLaunchKernelGGL(rowmax_kernel, dim3(256), dim3(512), 0, stream, qb, kb, Mrow);
  hipLaunchKernelGGL(attn_kernel, dim3(256), dim3(512), 0, stream,
                     qb, kb, vb, Mrow, x, out);
}

// Round 20
// 70.381 us; speedup vs baseline: 1.4085x; 1.0394x over previous
//
#include <hip/hip_runtime.h>
#include <hip/hip_fp16.h>

typedef _Float16 half8 __attribute__((ext_vector_type(8)));
typedef _Float16 half2v __attribute__((ext_vector_type(2)));
typedef float f32x16 __attribute__((ext_vector_type(16)));
typedef float f32x4v __attribute__((ext_vector_type(4)));

#define MFMA16(A, B, C) __builtin_amdgcn_mfma_f32_32x32x16_f16((A), (B), (C), 0, 0, 0)

__device__ __forceinline__ f32x16 fzero16() {
  f32x16 z;
#pragma unroll
  for (int i = 0; i < 16; ++i) z[i] = 0.0f;
  return z;
}

__device__ __forceinline__ float max16(float vm, const f32x16& s) {
  const float g1 = fmaxf(fmaxf(s[0], s[1]), s[2]);
  const float g2 = fmaxf(fmaxf(s[3], s[4]), s[5]);
  const float g3 = fmaxf(fmaxf(s[6], s[7]), s[8]);
  const float g4 = fmaxf(fmaxf(s[9], s[10]), s[11]);
  const float g5 = fmaxf(fmaxf(s[12], s[13]), s[14]);
  const float h1 = fmaxf(fmaxf(g1, g2), g3);
  const float h2 = fmaxf(fmaxf(g4, g5), s[15]);
  return fmaxf(fmaxf(vm, h1), h2);
}

// ---------------------------------------------------------------------------
// wprep v3: plain-fp16 weights in MFMA-fragment layout; 40 blocks. (kept)
// ---------------------------------------------------------------------------
__global__ __launch_bounds__(256) void wprep_kernel(
    const float* __restrict__ w1, const float* __restrict__ w2,
    const float* __restrict__ w3,
    _Float16* __restrict__ w1p, _Float16* __restrict__ w2p,
    _Float16* __restrict__ w3p)
{
  const int t = threadIdx.x;
  const int blk = blockIdx.x;
  if (blk < 32) {
    const int cot = blk >> 2, sub = blk & 3;
    for (int e = sub * 2048 + t; e < sub * 2048 + 2048; e += 256) {
      const int j = e & 7, l = (e >> 3) & 63, cs = e >> 9;
      const int lr = l & 31, h = l >> 5;
      const int row = cot * 32 + lr;
      const int col = cs * 16 + 4 * h + (j & 3) + 8 * (j >> 2);
      w3p[((cot * 16 + cs) * 64 + l) * 8 + j] = (_Float16)w3[row * 256 + col];
    }
  } else {
    const int sub = blk - 32;   // 0..7
    for (int e = sub * 1024 + t; e < sub * 1024 + 1024; e += 256) {
      const int j = e & 7, l = (e >> 3) & 63, cs = e >> 9;
      const int lr = l & 31, h = l >> 5;
      const int col = cs * 16 + 4 * h + (j & 3) + 8 * (j >> 2);
      const int idx = (cs * 64 + l) * 8 + j;
      w1p[idx] = (_Float16)w1[lr * 256 + col];
      w2p[idx] = (_Float16)w2[lr * 256 + col];
    }
  }
}

// ---------------------------------------------------------------------------
// FUSED qkv projection v4 — plain fp16 + software pipeline: x column (float
// regs) and w3p fragments for cs+1 staged while MFMAing cs. Math identical.
// ---------------------------------------------------------------------------
__global__ __launch_bounds__(256) void qkv_proj_kernel(
    const float* __restrict__ x,
    const _Float16* __restrict__ w1p, const float* __restrict__ b1,
    const _Float16* __restrict__ w2p, const float* __restrict__ b2,
    const _Float16* __restrict__ w3p, const float* __restrict__ b3,
    _Float16* __restrict__ qb, _Float16* __restrict__ kb,
    _Float16* __restrict__ vb)
{
  __shared__ f32x4v red[4][2][4][64];   // [wave][q/k][i4][lane], 32 KB
  const int t = threadIdx.x, w = t >> 6, l = t & 63;
  const int lr = l & 31, h = l >> 5;
  const int b = blockIdx.x >> 7;
  const int nt = blockIdx.x & 127;
  const float* xb = x + (size_t)b * 256 * 4096 + nt * 32 + lr;
  const int cot0 = w * 2, cot1 = w * 2 + 1;

  f32x16 accq = fzero16(), acck = fzero16();
  f32x16 accv0 = fzero16(), accv1 = fzero16();

#define LOADX(CS, XF)                                                          \
  {                                                                            \
    const int c0_ = (CS) * 16 + 4 * h;                                         \
    _Pragma("unroll") for (int j = 0; j < 8; ++j)                              \
      XF[j] = xb[(size_t)(c0_ + (j & 3) + 8 * (j >> 2)) * 4096];               \
  }
#define LOADW3(CS, W0, W1)                                                     \
  {                                                                            \
    W0 = *(const half8*)&w3p[((cot0 * 16 + (CS)) * 64 + l) * 8];               \
    W1 = *(const half8*)&w3p[((cot1 * 16 + (CS)) * 64 + l) * 8];               \
  }
#define STEP(CS, XF, W0, W1)                                                   \
  {                                                                            \
    half8 xh;                                                                  \
    _Pragma("unroll") for (int j = 0; j < 8; ++j) xh[j] = (_Float16)XF[j];     \
    accv0 = MFMA16(xh, W0, accv0);                                             \
    accv1 = MFMA16(xh, W1, accv1);                                             \
    if (((CS) >> 2) == w) {                                                    \
      const half8 w1h = *(const half8*)&w1p[((CS) * 64 + l) * 8];              \
      const half8 w2h = *(const half8*)&w2p[((CS) * 64 + l) * 8];              \
      accq = MFMA16(w1h, xh, accq);                                            \
      acck = MFMA16(w2h, xh, acck);                                            \
    }                                                                          \
  }

  float xfA[8], xfB[8];
  half8 w3A0, w3A1, w3B0, w3B1;
  LOADX(0, xfA)
  LOADW3(0, w3A0, w3A1)
#pragma unroll
  for (int cs = 0; cs < 16; cs += 2) {
    if (cs + 1 < 16) { LOADX(cs + 1, xfB) LOADW3(cs + 1, w3B0, w3B1) }
    STEP(cs, xfA, w3A0, w3A1)
    if (cs + 2 < 16) { LOADX(cs + 2, xfA) LOADW3(cs + 2, w3A0, w3A1) }
    STEP(cs + 1, xfB, w3B0, w3B1)
  }
#undef STEP
#undef LOADW3
#undef LOADX

  const float bv0 = b3[cot0 * 32 + lr];
  const float bv1 = b3[cot1 * 32 + lr];
#pragma unroll
  for (int hfq = 0; hfq < 2; ++hfq) {
    half8 p0, p1;
#pragma unroll
    for (int j = 0; j < 8; ++j) {
      p0[j] = (_Float16)(accv0[8 * hfq + j] + bv0);
      p1[j] = (_Float16)(accv1[8 * hfq + j] + bv1);
    }
    const int ms = nt * 2 + hfq;
    *(half8*)&vb[((((size_t)b * 256 + ms) * 8 + cot0) * 64 + l) * 8] = p0;
    *(half8*)&vb[((((size_t)b * 256 + ms) * 8 + cot1) * 64 + l) * 8] = p1;
  }

#pragma unroll
  for (int i4 = 0; i4 < 4; ++i4) {
    f32x4v q4, k4;
#pragma unroll
    for (int c = 0; c < 4; ++c) { q4[c] = accq[4 * i4 + c]; k4[c] = acck[4 * i4 + c]; }
    red[w][0][i4][l] = q4;
    red[w][1][i4][l] = k4;
  }
  __syncthreads();
  if (w < 2) {
    _Float16* dst = (w == 0) ? qb : kb;
    const float* bias = (w == 0) ? b1 : b2;
    f32x16 tot;
#pragma unroll
    for (int i4 = 0; i4 < 4; ++i4) {
      f32x4v v = red[0][w][i4][l];
      v += red[1][w][i4][l];
      v += red[2][w][i4][l];
      v += red[3][w][i4][l];
#pragma unroll
      for (int c = 0; c < 4; ++c) tot[4 * i4 + c] = v[c];
    }
#pragma unroll
    for (int ds = 0; ds < 2; ++ds) {
      half8 ph;
#pragma unroll
      for (int j = 0; j < 8; ++j) {
        const int d = 16 * ds + 4 * h + (j & 3) + 8 * (j >> 2);
        ph[j] = (_Float16)(tot[8 * ds + j] + bias[d]);
      }
      *(half8*)&dst[((((size_t)b * 128 + nt) * 2 + ds) * 64 + l) * 8] = ph;
    }
  }
}

// ---------------------------------------------------------------------------
// rowmax v5 = v4 + depth-1 K prefetch (register rotation). MFMA operand order
// unchanged -> bitwise-identical S to attn QK.
// ---------------------------------------------------------------------------
__global__ __launch_bounds__(512) void rowmax_kernel(
    const _Float16* __restrict__ qb, const _Float16* __restrict__ kb,
    float* __restrict__ Mrow)
{
  __shared__ float red[2][8][32];
  const int t = threadIdx.x, w = t >> 6, l = t & 63;
  const int bid = blockIdx.x;
  const int xcd = bid & 7;
  const int b = xcd >> 1;
  const int sp = ((bid >> 3) << 1) | (xcd & 1);   // slab pair [0,64)
  const int sl0 = sp * 2, sl1 = sp * 2 + 1;
  const _Float16* qp0 = qb + ((((size_t)b * 128 + sl0) * 2) * 64 + l) * 8;
  const _Float16* qp1 = qb + ((((size_t)b * 128 + sl1) * 2) * 64 + l) * 8;
  const half8 q00 = *(const half8*)qp0;
  const half8 q01 = *(const half8*)(qp0 + 512);
  const half8 q10 = *(const half8*)qp1;
  const half8 q11 = *(const half8*)(qp1 + 512);
  float vm0 = -3.0e38f, vm1 = -3.0e38f;
  const int mt0 = w * 16, mtE = w * 16 + 16;
  half8 k0 = *(const half8*)(kb + ((((size_t)b * 128 + mt0) * 2) * 64 + l) * 8);
  half8 k1 = *(const half8*)(kb + ((((size_t)b * 128 + mt0) * 2 + 1) * 64 + l) * 8);
  for (int mt = mt0; mt < mtE; ++mt) {
    half8 n0, n1;
    if (mt + 1 < mtE) {
      const _Float16* kp = kb + ((((size_t)b * 128 + mt + 1) * 2) * 64 + l) * 8;
      n0 = *(const half8*)kp;
      n1 = *(const half8*)(kp + 512);
    }
    f32x16 s0 = fzero16();
    s0 = MFMA16(k0, q00, s0);
    s0 = MFMA16(k1, q01, s0);
    f32x16 s1 = fzero16();
    s1 = MFMA16(k0, q10, s1);
    s1 = MFMA16(k1, q11, s1);
    vm0 = max16(vm0, s0);
    vm1 = max16(vm1, s1);
    k0 = n0; k1 = n1;
  }
  vm0 = fmaxf(vm0, __shfl_xor(vm0, 32));
  vm1 = fmaxf(vm1, __shfl_xor(vm1, 32));
  if (l < 32) { red[0][w][l] = vm0; red[1][w][l] = vm1; }
  __syncthreads();
  if (t < 64) {
    const int slab = t >> 5, r = t & 31;
    float m = red[slab][0][r];
#pragma unroll
    for (int ww = 1; ww < 8; ++ww) m = fmaxf(m, red[slab][ww][r]);
    Mrow[(size_t)b * 4096 + (sp * 2 + slab) * 32 + r] = m;
  }
}

// ---------------------------------------------------------------------------
// attn v8 VERBATIM (measured 51.3us best): balanced producer/consumer waves,
// one barrier per 256 keys, deep reg prefetch, union pack.
// ---------------------------------------------------------------------------
__global__ __launch_bounds__(512, 1) void attn_kernel(
    const _Float16* __restrict__ qb, const _Float16* __restrict__ kb,
    const _Float16* __restrict__ vb, const float* __restrict__ Mrow,
    const float* __restrict__ x, float* __restrict__ out)
{
  __shared__ __align__(16) _Float16 Plds[2][2][2][8][64][8];  // 64 KB
  __shared__ float Lred[2][4][32];
  const int t = threadIdx.x, w = t >> 6, l = t & 63;
  const int lr = l & 31, h = l >> 5;
  const int bid = blockIdx.x;
  const int xcd = bid & 7;
  const int b = xcd >> 1;
  const int rg = ((bid >> 3) << 1) | (xcd & 1);   // row-group of 64 [0,64)
  const int sw = w >> 2;                           // produced slab
  const int kq = w & 3;                            // produced key-quarter

  const _Float16* kbase = kb + (size_t)b * 131072 + (size_t)l * 8;
  const _Float16* vbase = vb + (size_t)b * 1048576 + (size_t)w * 512 + (size_t)l * 8;

#define KF(kt, ds) (*(const half8*)(kbase + ((size_t)(((kt) * 4 + kq) * 2 + (ds))) * 512))
#define VF(kt, ks) (*(const half8*)(vbase + ((size_t)(((kt) * 8 + (ks)) * 8)) * 512))

  const int rt32q = rg * 2 + sw;
  const _Float16* qp = qb + (((size_t)b * 128 + rt32q) * 2 * 64 + l) * 8;
  const half8 qf0 = *(const half8*)qp;
  const half8 qf1 = *(const half8*)(qp + 512);
  const float LOG2E = 1.44269504088896340736f;
  const float Mr = Mrow[(size_t)b * 4096 + rt32q * 32 + lr];
  const float nM2 = -Mr * LOG2E;

  f32x16 acc0 = fzero16(), acc1 = fzero16();
  float Lacc = 0.f;
  half8 va0[8], va1[8];
  half8 ka0, ka1, kb0_, kb1_;

#define EXPPACK(S, BUF, TI)                                                    \
  {                                                                            \
    float pvv[16];                                                             \
    float ls = 0.f;                                                            \
    _Pragma("unroll") for (int i = 0; i < 16; ++i) {                           \
      pvv[i] = exp2f(fmaf((S)[i], LOG2E, nM2)); ls += pvv[i];                  \
    }                                                                          \
    Lacc += ls;                                                                \
    union { half8 v; half2v h2[4]; } u0, u1;                                   \
    _Pragma("unroll") for (int jj = 0; jj < 4; ++jj) {                         \
      auto a0 = __builtin_amdgcn_cvt_pkrtz(pvv[2 * jj], pvv[2 * jj + 1]);      \
      auto a1 = __builtin_amdgcn_cvt_pkrtz(pvv[8 + 2 * jj], pvv[8 + 2 * jj + 1]); \
      u0.h2[jj] = *(half2v*)&a0;                                               \
      u1.h2[jj] = *(half2v*)&a1;                                               \
    }                                                                          \
    *(half8*)&Plds[BUF][TI][sw][kq * 2 + 0][l][0] = u0.v;                      \
    *(half8*)&Plds[BUF][TI][sw][kq * 2 + 1][l][0] = u1.v;                      \
  }

#define PVC(CB, TI, VA)                                                        \
  {                                                                            \
    __builtin_amdgcn_s_setprio(1);                                             \
    _Pragma("unroll") for (int ks = 0; ks < 8; ++ks) {                         \
      const half8 pb0 = *(const half8*)&Plds[CB][TI][0][ks][l][0];             \
      const half8 pb1 = *(const half8*)&Plds[CB][TI][1][ks][l][0];             \
      acc0 = MFMA16(VA[ks], pb0, acc0);                                        \
      acc1 = MFMA16(VA[ks], pb1, acc1);                                        \
    }                                                                          \
    __builtin_amdgcn_s_setprio(0);                                             \
  }

  // ---- prologue: V(0),V(1) in regs; produce tiles 0,1 -> buf0; K(2),K(3) ----
#pragma unroll
  for (int ks = 0; ks < 8; ++ks) va0[ks] = VF(0, ks);
#pragma unroll
  for (int ks = 0; ks < 8; ++ks) va1[ks] = VF(1, ks);
  {
    const half8 k00 = KF(0, 0), k01 = KF(0, 1);
    f32x16 s = fzero16();
    s = MFMA16(k00, qf0, s);
    s = MFMA16(k01, qf1, s);
    ka0 = KF(2, 0); ka1 = KF(2, 1);
    EXPPACK(s, 0, 0)
  }
  {
    const half8 k10 = KF(1, 0), k11 = KF(1, 1);
    f32x16 s = fzero16();
    s = MFMA16(k10, qf0, s);
    s = MFMA16(k11, qf1, s);
    kb0_ = KF(3, 0); kb1_ = KF(3, 1);
    EXPPACK(s, 0, 1)
  }
  asm volatile("s_waitcnt lgkmcnt(0)" ::: "memory");
  __builtin_amdgcn_s_barrier();
  asm volatile("" ::: "memory");

  // ---- 16 periods of 256 keys, ONE barrier each ----
  for (int P = 0; P < 16; ++P) {
    const int CB = P & 1, PB = CB ^ 1;
    const int p0 = 2 * P + 2, p1 = 2 * P + 3;

    if (p0 < 32) {
      f32x16 s = fzero16();
      s = MFMA16(ka0, qf0, s);
      s = MFMA16(ka1, qf1, s);
      if (p0 + 2 < 32) { ka0 = KF(p0 + 2, 0); ka1 = KF(p0 + 2, 1); }
      EXPPACK(s, PB, 0)
    }
    PVC(CB, 0, va0)
    if (p0 < 32) {
#pragma unroll
      for (int ks = 0; ks < 8; ++ks) va0[ks] = VF(p0, ks);
    }

    if (p1 < 32) {
      f32x16 s = fzero16();
      s = MFMA16(kb0_, qf0, s);
      s = MFMA16(kb1_, qf1, s);
      if (p1 + 2 < 32) { kb0_ = KF(p1 + 2, 0); kb1_ = KF(p1 + 2, 1); }
      EXPPACK(s, PB, 1)
    }
    PVC(CB, 1, va1)
    if (p1 < 32) {
#pragma unroll
      for (int ks = 0; ks < 8; ++ks) va1[ks] = VF(p1, ks);
    }

    asm volatile("s_waitcnt lgkmcnt(0)" ::: "memory");
    __builtin_amdgcn_s_barrier();
    asm volatile("" ::: "memory");
  }
#undef PVC
#undef EXPPACK
#undef KF
#undef VF

  // ---- L reduce: L[slab][row] = sum over 4 quarters ----
  {
    const float l2 = Lacc + __shfl_xor(Lacc, 32);
    if (l < 32) Lred[sw][kq][lr] = l2;
  }
  __syncthreads();
  const float invL0 = 1.0f / (Lred[0][0][lr] + Lred[0][1][lr] + Lred[0][2][lr] + Lred[0][3][lr]);
  const float invL1 = 1.0f / (Lred[1][0][lr] + Lred[1][1][lr] + Lred[1][2][lr] + Lred[1][3][lr]);

  // ---- epilogue: normalize + residual ----
  const float* xb = x + (size_t)b * 1048576;
  float* ob = out + (size_t)b * 1048576;
  const int nn0 = rg * 64 + lr;
  const int nn1 = rg * 64 + 32 + lr;
#pragma unroll
  for (int reg = 0; reg < 16; ++reg) {
    const int crel = (reg & 3) + 8 * (reg >> 2) + 4 * h;
    const int cout = w * 32 + crel;
    const size_t o0 = (size_t)cout * 4096 + nn0;
    ob[o0] = acc0[reg] * invL0 + xb[o0];
    const size_t o1 = (size_t)cout * 4096 + nn1;
    ob[o1] = acc1[reg] * invL1 + xb[o1];
  }
}

extern "C" void kernel_launch(void* const* d_in, const int* in_sizes, int n_in,
                              void* d_out, int out_size, void* d_ws, size_t ws_size,
                              hipStream_t stream) {
  const float* x  = (const float*)d_in[0];
  const float* w1 = (const float*)d_in[1];
  const float* b1 = (const float*)d_in[2];
  const float* w2 = (const float*)d_in[3];
  const float* b2 = (const float*)d_in[4];
  const float* w3 = (const float*)d_in[5];
  const float* b3 = (const float*)d_in[6];
  float* out = (float*)d_out;

  char* ws = (char*)d_ws;
  _Float16* qb  = (_Float16*)(ws);                               // 1 MB
  _Float16* kb  = (_Float16*)(ws + (1u << 20));                  // 1 MB
  _Float16* vb  = (_Float16*)(ws + (2u << 20));                  // 8 MB
  float*    Mrow = (float*)(ws + (10u << 20));                   // 64 KB
  _Float16* w1p = (_Float16*)(ws + (10u << 20) + (64u << 10));   // 16 KB
  _Float16* w2p = (_Float16*)(ws + (10u << 20) + (96u << 10));   // 16 KB
  _Float16* w3p = (_Float16*)(ws + (10u << 20) + (128u << 10));  // 128 KB

  hipLaunchKernelGGL(wprep_kernel, dim3(40), dim3(256), 0, stream,
                     w1, w2, w3, w1p, w2p, w3p);
  hipLaunchKernelGGL(qkv_proj_kernel, dim3(512), dim3(256), 0, stream,
                     x, w1p, b1, w2p, b2, w3p, b3, qb, kb, vb);
  hipLaunchKernelGGL(rowmax_kernel, dim3(256), dim3(512), 0, stream, qb, kb, Mrow);
  hipLaunchKernelGGL(attn_kernel, dim3(256), dim3(512), 0, stream,
                     qb, kb, vb, Mrow, x, out);
}